// Round 4
// baseline (1851.711 us; speedup 1.0000x reference)
//
#include <hip/hip_runtime.h>

// S5 associative scan, single-pass decoupled lookback.
// T=131072 timesteps, D=256 channels, fp32.
// combine(earlier=(Ai,Bi), later=(Aj,Bj)) = (Aj*Ai, Aj*Bi + Bj)
//
// 4096 blocks x 256 threads. Block c owns timesteps [c*32, c*32+32).
// Wave w (of 4) holds its 8 timesteps in registers (inputs read from HBM once).
// Wave aggregates combined via LDS; wave 0 publishes block aggregate (flag=1),
// looks back over predecessors (agent-scope atomics), publishes inclusive
// (flag=2); all waves then apply and NT-store outputs.

#define T_TOTAL 131072
#define D_DIM   256
#define TPW     8                     // timesteps per wave
#define WPB     4                     // waves per block
#define CHUNK   (TPW * WPB)           // 32 timesteps per block
#define NCHUNK  (T_TOTAL / CHUNK)     // 4096
#define NTHR    256

typedef float vfloat4 __attribute__((ext_vector_type(4)));
typedef float vfloat2 __attribute__((ext_vector_type(2)));
typedef unsigned long long u64;

// (ra,rb) = combine(earlier=(ra,rb), later=(ga,gb))
__device__ __forceinline__ void combine(vfloat4& ra, vfloat4& rb,
                                        const vfloat4 ga, const vfloat4 gb) {
    rb = ga * rb + gb;
    ra = ga * ra;
}

// (ra,rb) = combine(earlier=(pa,pb), later=(ra,rb))   [prepend predecessor]
__device__ __forceinline__ void combine_front(vfloat4& ra, vfloat4& rb,
                                              const vfloat4 pa, const vfloat4 pb) {
    rb = ra * pb + rb;   // uses old ra
    ra = ra * pa;
}

__device__ __forceinline__ void agent_store_f4(float* p, const vfloat4 v) {
    union { vfloat2 f; u64 u; } x0, x1;
    x0.f = (vfloat2){v.x, v.y};
    x1.f = (vfloat2){v.z, v.w};
    __hip_atomic_store((u64*)p,     x0.u, __ATOMIC_RELAXED, __HIP_MEMORY_SCOPE_AGENT);
    __hip_atomic_store((u64*)(p+2), x1.u, __ATOMIC_RELAXED, __HIP_MEMORY_SCOPE_AGENT);
}

__device__ __forceinline__ vfloat4 agent_load_f4(const float* p) {
    union { vfloat2 f; u64 u; } x0, x1;
    x0.u = __hip_atomic_load((const u64*)p,     __ATOMIC_RELAXED, __HIP_MEMORY_SCOPE_AGENT);
    x1.u = __hip_atomic_load((const u64*)(p+2), __ATOMIC_RELAXED, __HIP_MEMORY_SCOPE_AGENT);
    return (vfloat4){x0.f.x, x0.f.y, x1.f.x, x1.f.y};
}

__global__ void s5_init(unsigned* __restrict__ flags) {
    const int i = blockIdx.x * blockDim.x + threadIdx.x;
    if (i < NCHUNK) flags[i] = 0u;
}

__global__ __launch_bounds__(NTHR) void s5_scan(
    const float* __restrict__ A, const float* __restrict__ Bu,
    float* __restrict__ outA, float* __restrict__ outB,
    unsigned* __restrict__ flags,
    float* __restrict__ pAggA, float* __restrict__ pAggB,
    float* __restrict__ pIncA, float* __restrict__ pIncB)
{
    const int c    = blockIdx.x;
    const int tid  = threadIdx.x;
    const int w    = tid >> 6;        // wave 0..3
    const int lane = tid & 63;
    const int ch   = lane * 4;        // 4 channels per lane

    __shared__ float sA[WPB][D_DIM];  // per-wave aggregates
    __shared__ float sB[WPB][D_DIM];
    __shared__ float sPA[D_DIM];      // block-global exclusive prefix
    __shared__ float sPB[D_DIM];

    // ---- Phase A: load my wave's 8 timesteps into registers, aggregate ----
    const size_t base = (size_t)c * CHUNK * D_DIM + (size_t)w * TPW * D_DIM + ch;

    vfloat4 at[TPW], bt[TPW];
    #pragma unroll
    for (int t = 0; t < TPW; ++t)
        at[t] = __builtin_nontemporal_load((const vfloat4*)(A + base + (size_t)t * D_DIM));
    #pragma unroll
    for (int t = 0; t < TPW; ++t)
        bt[t] = __builtin_nontemporal_load((const vfloat4*)(Bu + base + (size_t)t * D_DIM));

    vfloat4 wa = {1.f, 1.f, 1.f, 1.f}, wb = {0.f, 0.f, 0.f, 0.f};
    #pragma unroll
    for (int t = 0; t < TPW; ++t) combine(wa, wb, at[t], bt[t]);

    *(vfloat4*)(&sA[w][ch]) = wa;
    *(vfloat4*)(&sB[w][ch]) = wb;
    __syncthreads();

    // ---- Cross-wave: exclusive prefix over waves [0,w) + block aggregate ----
    vfloat4 ewa = {1.f, 1.f, 1.f, 1.f}, ewb = {0.f, 0.f, 0.f, 0.f};
    vfloat4 bga = {1.f, 1.f, 1.f, 1.f}, bgb = {0.f, 0.f, 0.f, 0.f};
    #pragma unroll
    for (int i = 0; i < WPB; ++i) {
        const vfloat4 ga = *(const vfloat4*)(&sA[i][ch]);
        const vfloat4 gb = *(const vfloat4*)(&sB[i][ch]);
        if (i == w) { ewa = bga; ewb = bgb; }
        combine(bga, bgb, ga, gb);
    }

    // ---- Phase B (wave 0 only): publish, lookback, publish inclusive ----
    if (w == 0) {
        const size_t co = (size_t)c * D_DIM + ch;
        if (c == 0) {
            agent_store_f4(pIncA + co, bga);
            agent_store_f4(pIncB + co, bgb);
            __hip_atomic_store(&flags[0], 2u, __ATOMIC_RELEASE, __HIP_MEMORY_SCOPE_AGENT);
            *(vfloat4*)(&sPA[ch]) = (vfloat4){1.f, 1.f, 1.f, 1.f};
            *(vfloat4*)(&sPB[ch]) = (vfloat4){0.f, 0.f, 0.f, 0.f};
        } else {
            // publish aggregate so successors can proceed
            agent_store_f4(pAggA + co, bga);
            agent_store_f4(pAggB + co, bgb);
            __hip_atomic_store(&flags[c], 1u, __ATOMIC_RELEASE, __HIP_MEMORY_SCOPE_AGENT);

            // lookback: accumulate predecessor aggregates until an inclusive
            vfloat4 exA = {1.f, 1.f, 1.f, 1.f}, exB = {0.f, 0.f, 0.f, 0.f};
            int p = c - 1;
            while (true) {
                unsigned f;
                do {
                    f = __hip_atomic_load(&flags[p], __ATOMIC_RELAXED, __HIP_MEMORY_SCOPE_AGENT);
                } while (f == 0u);
                __builtin_amdgcn_fence(__ATOMIC_ACQUIRE, "agent");
                const size_t po = (size_t)p * D_DIM + ch;
                if (f == 2u) {
                    const vfloat4 ia = agent_load_f4(pIncA + po);
                    const vfloat4 ib = agent_load_f4(pIncB + po);
                    combine_front(exA, exB, ia, ib);
                    break;
                } else {
                    const vfloat4 ga = agent_load_f4(pAggA + po);
                    const vfloat4 gb = agent_load_f4(pAggB + po);
                    combine_front(exA, exB, ga, gb);
                    --p;
                }
            }

            // inclusive for this block = combine(earlier=ex, later=blockAgg)
            vfloat4 icA = exA, icB = exB;
            combine(icA, icB, bga, bgb);
            agent_store_f4(pIncA + co, icA);
            agent_store_f4(pIncB + co, icB);
            __hip_atomic_store(&flags[c], 2u, __ATOMIC_RELEASE, __HIP_MEMORY_SCOPE_AGENT);

            *(vfloat4*)(&sPA[ch]) = exA;
            *(vfloat4*)(&sPB[ch]) = exB;
        }
    }
    __syncthreads();

    // ---- Phase C: apply prefix, write outputs from registers ----
    const vfloat4 pa = *(const vfloat4*)(&sPA[ch]);
    const vfloat4 pb = *(const vfloat4*)(&sPB[ch]);

    // my wave's running state = combine(earlier=(pa,pb), later=(ewa,ewb))
    vfloat4 ra = ewa * pa;
    vfloat4 rb = ewa * pb + ewb;

    #pragma unroll
    for (int t = 0; t < TPW; ++t) {
        const size_t o = base + (size_t)t * D_DIM;
        combine(ra, rb, at[t], bt[t]);
        __builtin_nontemporal_store(ra, (vfloat4*)(outA + o));
        __builtin_nontemporal_store(rb, (vfloat4*)(outB + o));
    }
}

extern "C" void kernel_launch(void* const* d_in, const int* in_sizes, int n_in,
                              void* d_out, int out_size, void* d_ws, size_t ws_size,
                              hipStream_t stream)
{
    const float* A  = (const float*)d_in[0];
    const float* Bu = (const float*)d_in[1];
    float* outA = (float*)d_out;
    float* outB = (float*)d_out + (size_t)T_TOTAL * D_DIM;

    // workspace: flags (16 KB, padded to 32 KB) + 4 payload arrays of 4 MB
    unsigned* flags = (unsigned*)d_ws;
    float* pay  = (float*)d_ws + 8192;                 // 32 KB offset
    float* pAggA = pay;
    float* pAggB = pAggA + (size_t)NCHUNK * D_DIM;
    float* pIncA = pAggB + (size_t)NCHUNK * D_DIM;
    float* pIncB = pIncA + (size_t)NCHUNK * D_DIM;

    s5_init<<<(NCHUNK + 255) / 256, 256, 0, stream>>>(flags);
    s5_scan<<<NCHUNK, NTHR, 0, stream>>>(A, Bu, outA, outB, flags,
                                         pAggA, pAggB, pIncA, pIncB);
}